// Round 2
// baseline (1104.562 us; speedup 1.0000x reference)
//
#include <hip/hip_runtime.h>
#include <stdint.h>

typedef unsigned short u16;
typedef __bf16 bf16x8 __attribute__((ext_vector_type(8)));
typedef float  f32x4  __attribute__((ext_vector_type(4)));

#define D_MODEL 2048
#define SEQ     4096
#define NROWS   16384     // B*S = 4*4096
#define THREE_D 6144
#define K_SIZE  4

__device__ __forceinline__ float b2f(u16 u) {
    union { uint32_t i; float f; } v; v.i = ((uint32_t)u) << 16; return v.f;
}
__device__ __forceinline__ u16 f2b(float f) {
    uint32_t u = __builtin_bit_cast(uint32_t, f);
    u += 0x7fff + ((u >> 16) & 1);          // RNE
    return (u16)(u >> 16);
}

// ---------------- fp32 -> bf16 cast (8 elems/thread) ----------------
__global__ __launch_bounds__(256) void cast_f32_to_bf16(
    const float* __restrict__ src, u16* __restrict__ dst, int n8)
{
    int i = blockIdx.x * blockDim.x + threadIdx.x;
    if (i >= n8) return;
    const float4* s = (const float4*)src + (size_t)i * 2;
    float4 a = s[0], b = s[1];
    union { u16 u[8]; uint4 v; } o;
    o.u[0] = f2b(a.x); o.u[1] = f2b(a.y); o.u[2] = f2b(a.z); o.u[3] = f2b(a.w);
    o.u[4] = f2b(b.x); o.u[5] = f2b(b.y); o.u[6] = f2b(b.z); o.u[7] = f2b(b.w);
    *(uint4*)(dst + (size_t)i * 8) = o.v;
}

// ---------------- conv_w [D,1,K] -> cwt [K,D] transpose ----------------
__global__ __launch_bounds__(256) void prep_cwt(
    const float* __restrict__ cw, float* __restrict__ cwt)
{
    int i = blockIdx.x * blockDim.x + threadIdx.x;
    if (i >= D_MODEL * K_SIZE) return;
    int d = i >> 2, k = i & 3;
    cwt[k * D_MODEL + d] = cw[i];
}

// ---------------- bf16 NT GEMM: C[M,N] = A[M,K] * B[N,K]^T ----------------
// 128x128 tile, BK=32, 4 waves (2x2), each wave 4x4 of 16x16x32 MFMA.
// LDS k-chunk swizzle: element (row, c) stored at slot (c + (row>>1)) & 3
// -> fragment b128 reads spread over all 8 bank groups (2-way = free, m136).
// Grid: 1D, L2-swizzled (8 M-tiles x all N-tiles per group -> 4MB A set).
template<int BF16OUT>
__global__ __launch_bounds__(256) void gemm_bt(
    const u16* __restrict__ A, const u16* __restrict__ B,
    void* __restrict__ Cout, int M, int N, int K, int num_n)
{
    __shared__ u16 lA[128 * 32];   // 8 KiB
    __shared__ u16 lB[128 * 32];   // 8 KiB

    const int tid  = threadIdx.x;
    const int lane = tid & 63;
    const int wave = tid >> 6;
    const int wm = (wave >> 1) * 64;
    const int wn = (wave & 1) * 64;

    // L2-friendly decomposition of the 1D grid
    const int GM = 8;                            // M-tiles per group
    const int idx   = blockIdx.x;
    const int group = idx / (GM * num_n);
    const int rem   = idx - group * (GM * num_n);
    const int bn = rem / GM;
    const int bm = group * GM + (rem - bn * GM);

    // staging: per pass, 256 threads x 16B = 4KiB; each 8KiB tile needs 2 passes.
    // LDS dest (HW) = uniform_base + lane*16B -> slot (row = pass*64+wave*16+lane>>2,
    // c_slot = lane&3). Swizzle: slot c_slot holds global chunk (c_slot - (row>>1))&3.
    // (row>>1)&3 is pass- and wave-invariant = (lane>>3)&3.
    const int srow   = lane >> 2;
    const int c_glob = ((lane & 3) - ((lane >> 3) & 3)) & 3;
    const size_t strideK = (size_t)K;

    const u16* ga0 = A + ((size_t)(bm * 128) + wave * 16 + srow) * strideK + c_glob * 8;
    const u16* gb0 = B + ((size_t)(bn * 128) + wave * 16 + srow) * strideK + c_glob * 8;

    u16* lA0 = lA + wave * 512;          // bytes: wave*1024
    u16* lA1 = lA + 2048 + wave * 512;   // + pass*4096
    u16* lB0 = lB + wave * 512;
    u16* lB1 = lB + 2048 + wave * 512;

    f32x4 acc[4][4] = {};

    const int fr = lane & 15;   // fragment row (A) / col (B,D)
    const int fq = lane >> 4;   // quad
    // read-side swizzled chunk: (fq + (row>>1))&3 with row = {wm|wn}+i*16+fr;
    // wm/wn/i*16 contribute 0 mod 4 after >>1, so chunk = (fq + (fr>>1)) & 3.
    const int csw = (fq + (fr >> 1)) & 3;

    for (int kk = 0; kk < K; kk += 32) {
        __builtin_amdgcn_global_load_lds(
            (const __attribute__((address_space(1))) void*)(ga0 + kk),
            (__attribute__((address_space(3))) void*)lA0, 16, 0, 0);
        __builtin_amdgcn_global_load_lds(
            (const __attribute__((address_space(1))) void*)(ga0 + 64 * strideK + kk),
            (__attribute__((address_space(3))) void*)lA1, 16, 0, 0);
        __builtin_amdgcn_global_load_lds(
            (const __attribute__((address_space(1))) void*)(gb0 + kk),
            (__attribute__((address_space(3))) void*)lB0, 16, 0, 0);
        __builtin_amdgcn_global_load_lds(
            (const __attribute__((address_space(1))) void*)(gb0 + 64 * strideK + kk),
            (__attribute__((address_space(3))) void*)lB1, 16, 0, 0);
        __syncthreads();   // drains vmcnt (global_load_lds) before LDS reads

        bf16x8 af[4], bfv[4];
        #pragma unroll
        for (int i = 0; i < 4; i++)
            af[i] = *(const bf16x8*)&lA[(wm + i * 16 + fr) * 32 + csw * 8];
        #pragma unroll
        for (int j = 0; j < 4; j++)
            bfv[j] = *(const bf16x8*)&lB[(wn + j * 16 + fr) * 32 + csw * 8];

        #pragma unroll
        for (int i = 0; i < 4; i++)
            #pragma unroll
            for (int j = 0; j < 4; j++)
                acc[i][j] = __builtin_amdgcn_mfma_f32_16x16x32_bf16(
                    af[i], bfv[j], acc[i][j], 0, 0, 0);
        __syncthreads();   // protect LDS from next-iter staging
    }

    // epilogue: D[m][n] -> col = lane&15, row = (lane>>4)*4 + reg   [m89-verified]
    const int row0 = bm * 128 + wm + fq * 4;
    const int col0 = bn * 128 + wn + fr;
    if (BF16OUT) {
        u16* C = (u16*)Cout;
        #pragma unroll
        for (int i = 0; i < 4; i++)
            #pragma unroll
            for (int j = 0; j < 4; j++)
                #pragma unroll
                for (int r = 0; r < 4; r++)
                    C[(size_t)(row0 + i * 16 + r) * N + (col0 + j * 16)] = f2b(acc[i][j][r]);
    } else {
        float* C = (float*)Cout;
        #pragma unroll
        for (int i = 0; i < 4; i++)
            #pragma unroll
            for (int j = 0; j < 4; j++)
                #pragma unroll
                for (int r = 0; r < 4; r++)
                    C[(size_t)(row0 + i * 16 + r) * N + (col0 + j * 16)] = acc[i][j][r];
    }
}

// ---------------- gate + causal depthwise conv + gate2 ----------------
// z[n,d] = Cg[n,d] * sum_{k=0..3} Bg[n-3+k,d]*Xg[n-3+k,d]*cw[d,k]
// BCx row layout: [Bg(0..2047) | Cg(2048..4095) | Xg(4096..6143)]
__global__ __launch_bounds__(256) void gate_conv(
    const u16* __restrict__ BCx, const float* __restrict__ cwt, u16* __restrict__ z)
{
    const int n  = blockIdx.x;              // 0..16383
    const int dg = threadIdx.x << 3;        // 8 channels per thread
    const int s  = n & (SEQ - 1);
    const u16* base = BCx + (size_t)n * THREE_D;

    float conv[8];
    #pragma unroll
    for (int j = 0; j < 8; j++) conv[j] = 0.f;

    #pragma unroll
    for (int r = 0; r < 4; r++) {           // tap index k = r, source row n-3+r
        const int back = 3 - r;
        if (s >= back) {                    // block-uniform branch
            const u16* pb = base - (size_t)back * THREE_D + dg;
            union { uint4 v; u16 u[8]; } ub, ux;
            ub.v = *(const uint4*)pb;                    // Bg
            ux.v = *(const uint4*)(pb + 2 * D_MODEL);    // Xg
            const float* w = cwt + r * D_MODEL + dg;
            float4 w0 = *(const float4*)w;
            float4 w1 = *(const float4*)(w + 4);
            float ww[8] = { w0.x, w0.y, w0.z, w0.w, w1.x, w1.y, w1.z, w1.w };
            #pragma unroll
            for (int j = 0; j < 8; j++)
                conv[j] += b2f(ub.u[j]) * b2f(ux.u[j]) * ww[j];
        }
    }

    union { uint4 v; u16 u[8]; } uc, uo;
    uc.v = *(const uint4*)(base + D_MODEL + dg);         // Cg
    #pragma unroll
    for (int j = 0; j < 8; j++)
        uo.u[j] = f2b(b2f(uc.u[j]) * conv[j]);
    *(uint4*)(z + (size_t)n * D_MODEL + dg) = uo.v;
}

extern "C" void kernel_launch(void* const* d_in, const int* in_sizes, int n_in,
                              void* d_out, int out_size, void* d_ws, size_t ws_size,
                              hipStream_t stream) {
    const float* x  = (const float*)d_in[0];   // [4,4096,2048]
    const float* w1 = (const float*)d_in[1];   // [6144,2048]
    const float* w2 = (const float*)d_in[2];   // [2048,2048]
    const float* cw = (const float*)d_in[3];   // [2048,1,4]
    float* out = (float*)d_out;                // [4,4096,2048] fp32

    // workspace layout (bytes), all 16B-aligned:
    char* ws = (char*)d_ws;
    u16*   xb  = (u16*)(ws);                       //  64 MiB  bf16 x
    u16*   w1b = (u16*)(ws + 67108864);            //  24 MiB  bf16 w1
    u16*   w2b = (u16*)(ws + 92274688);            //   8 MiB  bf16 w2
    float* cwt = (float*)(ws + 100663296);         //  32 KiB  conv_w transposed [K,D]
    u16*   bcx = (u16*)(ws + 100696064);           // 192 MiB  BCx bf16 [16384,6144]
    u16*   z   = (u16*)(ws + 302022656);           //  64 MiB  z bf16 [16384,2048]

    cast_f32_to_bf16<<<dim3((4194304 + 255) / 256), 256, 0, stream>>>(x,  xb,  4194304);
    cast_f32_to_bf16<<<dim3((1572864 + 255) / 256), 256, 0, stream>>>(w1, w1b, 1572864);
    cast_f32_to_bf16<<<dim3((524288  + 255) / 256), 256, 0, stream>>>(w2, w2b, 524288);
    prep_cwt<<<dim3(32), 256, 0, stream>>>(cw, cwt);

    // GEMM1: BCx = x @ w1^T   [16384,6144]
    gemm_bt<1><<<dim3(128 * 48), 256, 0, stream>>>(xb, w1b, (void*)bcx, NROWS, THREE_D, D_MODEL, 48);
    // gate + conv -> z bf16 [16384,2048]
    gate_conv<<<dim3(NROWS), 256, 0, stream>>>(bcx, cwt, z);
    // GEMM2: out = z @ w2^T   [16384,2048] fp32
    gemm_bt<0><<<dim3(128 * 16), 256, 0, stream>>>(z, w2b, (void*)out, NROWS, D_MODEL, D_MODEL, 16);
}

// Round 3
// 875.050 us; speedup vs baseline: 1.2623x; 1.2623x over previous
//
#include <hip/hip_runtime.h>
#include <stdint.h>

typedef unsigned short u16;
typedef __bf16 bf16x8 __attribute__((ext_vector_type(8)));
typedef float  f32x4  __attribute__((ext_vector_type(4)));

#define D_MODEL 2048
#define SEQ     4096
#define NROWS   16384     // B*S = 4*4096
#define THREE_D 6144
#define K_SIZE  4

__device__ __forceinline__ float b2f(u16 u) {
    union { uint32_t i; float f; } v; v.i = ((uint32_t)u) << 16; return v.f;
}
__device__ __forceinline__ u16 f2b(float f) {
    uint32_t u = __builtin_bit_cast(uint32_t, f);
    u += 0x7fff + ((u >> 16) & 1);          // RNE
    return (u16)(u >> 16);
}

// ---------------- fp32 -> bf16 cast (8 elems/thread) ----------------
__global__ __launch_bounds__(256) void cast_f32_to_bf16(
    const float* __restrict__ src, u16* __restrict__ dst, int n8)
{
    int i = blockIdx.x * blockDim.x + threadIdx.x;
    if (i >= n8) return;
    const float4* s = (const float4*)src + (size_t)i * 2;
    float4 a = s[0], b = s[1];
    union { u16 u[8]; uint4 v; } o;
    o.u[0] = f2b(a.x); o.u[1] = f2b(a.y); o.u[2] = f2b(a.z); o.u[3] = f2b(a.w);
    o.u[4] = f2b(b.x); o.u[5] = f2b(b.y); o.u[6] = f2b(b.z); o.u[7] = f2b(b.w);
    *(uint4*)(dst + (size_t)i * 8) = o.v;
}

// ---------------- conv_w [D,1,K] -> cwt [K,D] transpose ----------------
__global__ __launch_bounds__(256) void prep_cwt(
    const float* __restrict__ cw, float* __restrict__ cwt)
{
    int i = blockIdx.x * blockDim.x + threadIdx.x;
    if (i >= D_MODEL * K_SIZE) return;
    int d = i >> 2, k = i & 3;
    cwt[k * D_MODEL + d] = cw[i];
}

// ---------------- bf16 NT GEMM: C[M,N] = A[M,K] * B[N,K]^T ----------------
// 128x128 tile, BK=64 (32 MFMA per barrier round), 4 waves (2x2), each wave
// 4x4 of 16x16x32 MFMA over two k-halves.
// LDS layout: [row][64 u16], 16B chunk c of row r stored at slot c ^ (r&7)
//   -> staging satisfies wave-uniform-base+lane*16, and b128 fragment reads
//      spread 8 touches/bank (conflict-free minimum).
// Grid: 1D; xcd = idx&7 owns an N-slice (n_per_xcd tiles, B slice L2-resident);
//   within XCD, bm-major so A streams with near-concurrent 6x reuse.
template<int BF16OUT>
__global__ __launch_bounds__(256, 3) void gemm_bt(
    const u16* __restrict__ A, const u16* __restrict__ B,
    void* __restrict__ Cout, int N, int K, int n_per_xcd)
{
    __shared__ u16 lA[128 * 64];   // 16 KiB
    __shared__ u16 lB[128 * 64];   // 16 KiB

    const int tid  = threadIdx.x;
    const int lane = tid & 63;
    const int wave = tid >> 6;
    const int wm = (wave >> 1) * 64;
    const int wn = (wave & 1) * 64;

    // XCD-aware mapping (idx&7 ~ XCD round-robin heuristic; safe if wrong)
    const int idx   = blockIdx.x;
    const int xcd   = idx & 7;
    const int local = idx >> 3;
    const int bm  = local / n_per_xcd;                    // 0..127, B-slice stays hot
    const int bn  = xcd * n_per_xcd + (local - bm * n_per_xcd);

    // staging: per pass, 256 threads x 16B = 4KiB = 32 rows; 4 passes per 16KiB tile.
    // lane -> row srow = lane>>3, slot = lane&7 holds global chunk (lane&7)^srow.
    const int srow = lane >> 3;                  // 0..7
    const int cg   = ((lane & 7) ^ srow) * 8;    // global col offset (u16)
    const size_t sK = (size_t)K;

    const u16* ga = A + ((size_t)(bm * 128) + wave * 8 + srow) * sK + cg;
    const u16* gb = B + ((size_t)(bn * 128) + wave * 8 + srow) * sK + cg;

    u16* lAw = lA + wave * 512;   // wave base: wave*1024 bytes
    u16* lBw = lB + wave * 512;

    f32x4 acc[4][4] = {};

    const int fr = lane & 15;   // fragment row (A) / col (B,D)
    const int fq = lane >> 4;   // quad
    // read slot for k-half h: (h*4+fq) ^ (fr&7); u16 offset = slot*8
    const int off0 = ((fq ^ (fr & 7)) * 8);
    const int off1 = off0 ^ 32;   // slot ^ 4  ->  +- 32 u16

    for (int kk = 0; kk < K; kk += 64) {
        #pragma unroll
        for (int p = 0; p < 4; p++) {
            __builtin_amdgcn_global_load_lds(
                (const __attribute__((address_space(1))) void*)(ga + (size_t)p * 32 * sK + kk),
                (__attribute__((address_space(3))) void*)(lAw + p * 2048), 16, 0, 0);
            __builtin_amdgcn_global_load_lds(
                (const __attribute__((address_space(1))) void*)(gb + (size_t)p * 32 * sK + kk),
                (__attribute__((address_space(3))) void*)(lBw + p * 2048), 16, 0, 0);
        }
        __syncthreads();   // drains vmcnt (global_load_lds) before LDS reads

        bf16x8 a0[4], b0[4], a1[4], b1[4];
        #pragma unroll
        for (int i = 0; i < 4; i++) {
            a0[i] = *(const bf16x8*)&lA[(wm + i * 16 + fr) * 64 + off0];
            b0[i] = *(const bf16x8*)&lB[(wn + i * 16 + fr) * 64 + off0];
        }
        #pragma unroll
        for (int i = 0; i < 4; i++) {
            a1[i] = *(const bf16x8*)&lA[(wm + i * 16 + fr) * 64 + off1];
            b1[i] = *(const bf16x8*)&lB[(wn + i * 16 + fr) * 64 + off1];
        }

        #pragma unroll
        for (int i = 0; i < 4; i++)
            #pragma unroll
            for (int j = 0; j < 4; j++)
                acc[i][j] = __builtin_amdgcn_mfma_f32_16x16x32_bf16(
                    a0[i], b0[j], acc[i][j], 0, 0, 0);
        #pragma unroll
        for (int i = 0; i < 4; i++)
            #pragma unroll
            for (int j = 0; j < 4; j++)
                acc[i][j] = __builtin_amdgcn_mfma_f32_16x16x32_bf16(
                    a1[i], b1[j], acc[i][j], 0, 0, 0);

        __syncthreads();   // protect LDS from next-iter staging
    }

    // epilogue: D[m][n] -> col = lane&15, row = (lane>>4)*4 + reg   [m89-verified]
    const int row0 = bm * 128 + wm + fq * 4;
    const int col0 = bn * 128 + wn + fr;
    if (BF16OUT) {
        u16* C = (u16*)Cout;
        #pragma unroll
        for (int i = 0; i < 4; i++)
            #pragma unroll
            for (int j = 0; j < 4; j++)
                #pragma unroll
                for (int r = 0; r < 4; r++)
                    C[(size_t)(row0 + i * 16 + r) * N + (col0 + j * 16)] = f2b(acc[i][j][r]);
    } else {
        float* C = (float*)Cout;
        #pragma unroll
        for (int i = 0; i < 4; i++)
            #pragma unroll
            for (int j = 0; j < 4; j++)
                #pragma unroll
                for (int r = 0; r < 4; r++)
                    C[(size_t)(row0 + i * 16 + r) * N + (col0 + j * 16)] = acc[i][j][r];
    }
}

// ---------------- gate + causal depthwise conv + gate2 ----------------
// z[n,d] = Cg[n,d] * sum_{k=0..3} Bg[n-3+k,d]*Xg[n-3+k,d]*cw[d,k]
// BCx row layout: [Bg(0..2047) | Cg(2048..4095) | Xg(4096..6143)]
__global__ __launch_bounds__(256) void gate_conv(
    const u16* __restrict__ BCx, const float* __restrict__ cwt, u16* __restrict__ z)
{
    const int n  = blockIdx.x;              // 0..16383
    const int dg = threadIdx.x << 3;        // 8 channels per thread
    const int s  = n & (SEQ - 1);
    const u16* base = BCx + (size_t)n * THREE_D;

    float conv[8];
    #pragma unroll
    for (int j = 0; j < 8; j++) conv[j] = 0.f;

    #pragma unroll
    for (int r = 0; r < 4; r++) {           // tap index k = r, source row n-3+r
        const int back = 3 - r;
        if (s >= back) {                    // block-uniform branch
            const u16* pb = base - (size_t)back * THREE_D + dg;
            union { uint4 v; u16 u[8]; } ub, ux;
            ub.v = *(const uint4*)pb;                    // Bg
            ux.v = *(const uint4*)(pb + 2 * D_MODEL);    // Xg
            const float* w = cwt + r * D_MODEL + dg;
            float4 w0 = *(const float4*)w;
            float4 w1 = *(const float4*)(w + 4);
            float ww[8] = { w0.x, w0.y, w0.z, w0.w, w1.x, w1.y, w1.z, w1.w };
            #pragma unroll
            for (int j = 0; j < 8; j++)
                conv[j] += b2f(ub.u[j]) * b2f(ux.u[j]) * ww[j];
        }
    }

    union { uint4 v; u16 u[8]; } uc, uo;
    uc.v = *(const uint4*)(base + D_MODEL + dg);         // Cg
    #pragma unroll
    for (int j = 0; j < 8; j++)
        uo.u[j] = f2b(b2f(uc.u[j]) * conv[j]);
    *(uint4*)(z + (size_t)n * D_MODEL + dg) = uo.v;
}

extern "C" void kernel_launch(void* const* d_in, const int* in_sizes, int n_in,
                              void* d_out, int out_size, void* d_ws, size_t ws_size,
                              hipStream_t stream) {
    const float* x  = (const float*)d_in[0];   // [4,4096,2048]
    const float* w1 = (const float*)d_in[1];   // [6144,2048]
    const float* w2 = (const float*)d_in[2];   // [2048,2048]
    const float* cw = (const float*)d_in[3];   // [2048,1,4]
    float* out = (float*)d_out;                // [4,4096,2048] fp32

    // workspace layout (bytes), all 16B-aligned:
    char* ws = (char*)d_ws;
    u16*   xb  = (u16*)(ws);                       //  64 MiB  bf16 x
    u16*   w1b = (u16*)(ws + 67108864);            //  24 MiB  bf16 w1
    u16*   w2b = (u16*)(ws + 92274688);            //   8 MiB  bf16 w2
    float* cwt = (float*)(ws + 100663296);         //  32 KiB  conv_w transposed [K,D]
    u16*   bcx = (u16*)(ws + 100696064);           // 192 MiB  BCx bf16 [16384,6144]
    u16*   z   = (u16*)(ws + 302022656);           //  64 MiB  z bf16 [16384,2048]

    cast_f32_to_bf16<<<dim3((4194304 + 255) / 256), 256, 0, stream>>>(x,  xb,  4194304);
    cast_f32_to_bf16<<<dim3((1572864 + 255) / 256), 256, 0, stream>>>(w1, w1b, 1572864);
    cast_f32_to_bf16<<<dim3((524288  + 255) / 256), 256, 0, stream>>>(w2, w2b, 524288);
    prep_cwt<<<dim3(32), 256, 0, stream>>>(cw, cwt);

    // GEMM1: BCx = x @ w1^T   [16384,6144]; 48 N-tiles = 6 per XCD
    gemm_bt<1><<<dim3(128 * 48), 256, 0, stream>>>(xb, w1b, (void*)bcx, THREE_D, D_MODEL, 6);
    // gate + conv -> z bf16 [16384,2048]
    gate_conv<<<dim3(NROWS), 256, 0, stream>>>(bcx, cwt, z);
    // GEMM2: out = z @ w2^T   [16384,2048] fp32; 16 N-tiles = 2 per XCD
    gemm_bt<0><<<dim3(128 * 16), 256, 0, stream>>>(z, w2b, (void*)out, D_MODEL, D_MODEL, 2);
}